// Round 2
// baseline (368.252 us; speedup 1.0000x reference)
//
#include <hip/hip_runtime.h>
#include <math.h>

// GATConv forward:
//   k_cast      : feat_bf = bf16(feat) into d_out scratch (dead until the
//                 final kernel overwrites it); Wbf = bf16(W) into ws.
//   k_gemm_mfma : feat_src(bf16) = feat @ W.T via mfma_f32_16x16x32_bf16.
//                 BK=64, A staged via global_load_lds (16B) with granule-XOR
//                 swizzle (source-side + read-side, rule #21), 1 barrier per
//                 chunk, 1-deep A prefetch. B fragments straight from L2-hot
//                 Wbf (no LDS). Fused el/er epilogue.
//   k_aggregate : per-dst edge softmax (deg==16) + weighted bf16 gather-sum.
//                 (unchanged: pinned at the random-gather L2-miss ceiling)
//
// N=100000, IN=256, H=4, D=64, E=N*16; degree uniformly 16 (row_ptr=arange*16).

#define HEADS 4
#define KIN 256
#define NOUT 256   // H*D
#define NEG_SLOPE 0.2f

typedef __attribute__((ext_vector_type(4))) short short4v;
typedef __attribute__((ext_vector_type(8))) short short8v;
typedef __attribute__((ext_vector_type(4))) float floatx4;

static __device__ __forceinline__ unsigned short f2bf(float x) {
  // round-to-nearest-even fp32 -> bf16 (inputs are normal; no NaN handling)
  unsigned u = __float_as_uint(x);
  u += 0x7FFFu + ((u >> 16) & 1u);
  return (unsigned short)(u >> 16);
}
static __device__ __forceinline__ float bf2f(unsigned short b) {
  return __uint_as_float(((unsigned)b) << 16);
}

// Grid-stride cast of feat (n4 float4s) -> feat_bf; first 16384 float4s of W
// -> Wbf piggyback on the first sweep (stride >= 524288 > 16384).
__global__ __launch_bounds__(256) void k_cast(
    const float* __restrict__ feat, const float* __restrict__ W,
    unsigned short* __restrict__ feat_bf, unsigned short* __restrict__ Wbf,
    int n4) {
  const int stride = gridDim.x * 256;
  for (int i = blockIdx.x * 256 + threadIdx.x; i < n4; i += stride) {
    float4 f = ((const float4*)feat)[i];
    ushort4 o;
    o.x = f2bf(f.x); o.y = f2bf(f.y); o.z = f2bf(f.z); o.w = f2bf(f.w);
    ((ushort4*)feat_bf)[i] = o;
    if (i < (NOUT * KIN / 4)) {
      float4 g = ((const float4*)W)[i];
      ushort4 p;
      p.x = f2bf(g.x); p.y = f2bf(g.y); p.z = f2bf(g.z); p.w = f2bf(g.w);
      ((ushort4*)Wbf)[i] = p;
    }
  }
}

// Block = 256 threads = 4 waves. Block tile: M=64 rows, N=256 (full width).
// Wave w owns cols [64w, 64w+64) == head w. Per wave: 4x4 grid of 16x16 MFMA
// tiles, K in 4 chunks of 64 (2 MFMA k-steps each).
//
// A LDS layout: linear [64 rows][64 k] bf16 per buffer (global_load_lds needs
// a linear dest). Swizzle: LDS 16B-slot (row, s) holds global granule
// s ^ (row&7)  -- achieved by XORing the *source* address per lane (m173
// pattern); reads apply the same XOR. Makes the stride-128B fragment read
// ~conflict-free (bank = 4*((g ^ row)&7) spans 8 banks over 16 rows).
__global__ __launch_bounds__(256, 3) void k_gemm_mfma(
    const unsigned short* __restrict__ feat_bf,
    const unsigned short* __restrict__ Wbf,
    const float* __restrict__ attn_l, const float* __restrict__ attn_r,
    unsigned short* __restrict__ fs_bf, float* __restrict__ el,
    float* __restrict__ er, int n_nodes) {
  __shared__ unsigned short Alds[2][64 * 64];  // 2 x 8 KB

  const int tid = threadIdx.x;
  const int lane = tid & 63;
  const int w = tid >> 6;      // wave = head = col-group
  const int m0 = blockIdx.x * 64;
  const int q = lane >> 4;     // quad 0..3
  const int l15 = lane & 15;

  floatx4 acc[4][4];
#pragma unroll
  for (int mt = 0; mt < 4; ++mt)
#pragma unroll
    for (int nt = 0; nt < 4; ++nt)
#pragma unroll
      for (int r = 0; r < 4; ++r) acc[mt][nt][r] = 0.0f;

  // ---- async A staging: wave w covers rows [16w, 16w+16), 2 instrs of 1KB.
  // Lane l -> (rsub = l>>3, g = l&7): LDS linear (row = s*8+rsub, slot g),
  // source granule g ^ rsub  (row&7 == rsub since 16w, 8s are 0 mod 8).
  const int rsub = lane >> 3;
  const int gg = lane & 7;
  const int sg = gg ^ rsub;  // swizzled source granule

  auto stage = [&](int kc, int b) {
#pragma unroll
    for (int s = 0; s < 2; ++s) {
      const int row = w * 16 + s * 8 + rsub;
      int gr = m0 + row;
      if (gr >= n_nodes) gr = n_nodes - 1;  // clamp tail (rows unused below)
      const unsigned short* src = feat_bf + (size_t)gr * KIN + kc * 64 + sg * 8;
      unsigned short* dst = &Alds[b][(w * 16 + s * 8) * 64];  // wave-uniform
      __builtin_amdgcn_global_load_lds(
          (const __attribute__((address_space(1))) unsigned int*)src,
          (__attribute__((address_space(3))) unsigned int*)dst, 16, 0, 0);
    }
  };

  stage(0, 0);
  for (int kc = 0; kc < 4; ++kc) {
    __syncthreads();  // drains vmcnt+lgkmcnt -> A(kc) staged by all waves;
                      // all waves done reading buf[(kc+1)&1] (chunk kc-1)
    if (kc < 3) stage(kc + 1, (kc + 1) & 1);

    // B fragments for this chunk straight from L2-hot Wbf:
    // lane(q,l15) needs B[n = 64w+16nt+l15][k = 64kc+32ks+8q .. +8]
    short8v bfr[2][4];
#pragma unroll
    for (int ks = 0; ks < 2; ++ks)
#pragma unroll
      for (int nt = 0; nt < 4; ++nt)
        bfr[ks][nt] = *(const short8v*)(Wbf + (size_t)(w * 64 + nt * 16 + l15) * KIN +
                                        kc * 64 + ks * 32 + q * 8);

#pragma unroll
    for (int ks = 0; ks < 2; ++ks) {
      short8v af[4];
#pragma unroll
      for (int mt = 0; mt < 4; ++mt) {
        const int slot = (ks * 4 + q) ^ (l15 & 7);  // un-swizzle on read
        af[mt] = *(const short8v*)(&Alds[kc & 1][(mt * 16 + l15) * 64 + slot * 8]);
      }
#pragma unroll
      for (int mt = 0; mt < 4; ++mt)
#pragma unroll
        for (int nt = 0; nt < 4; ++nt)
          acc[mt][nt] = __builtin_amdgcn_mfma_f32_16x16x32_bf16(
              af[mt], bfr[ks][nt], acc[mt][nt], 0, 0, 0);
    }
  }

  // ---- epilogue: C/D layout col = l15, row = q*4 + r (per 16x16 tile).
  // Store feat_src (bf16) + el/er from fp32 accumulators.
  float alv[4], arv[4];
#pragma unroll
  for (int nt = 0; nt < 4; ++nt) {
    alv[nt] = attn_l[w * 64 + nt * 16 + l15];
    arv[nt] = attn_r[w * 64 + nt * 16 + l15];
  }
#pragma unroll
  for (int mt = 0; mt < 4; ++mt) {
#pragma unroll
    for (int r = 0; r < 4; ++r) {
      const int m = m0 + mt * 16 + q * 4 + r;
      const bool mvalid = (m < n_nodes);
      float pl = 0.f, pr = 0.f;
#pragma unroll
      for (int nt = 0; nt < 4; ++nt) {
        const float v = acc[mt][nt][r];
        pl = fmaf(v, alv[nt], pl);
        pr = fmaf(v, arv[nt], pr);
        if (mvalid)
          fs_bf[(size_t)m * NOUT + w * 64 + nt * 16 + l15] = f2bf(v);
      }
      // reduce over the 16 lanes of this quad (same row m)
#pragma unroll
      for (int off = 1; off < 16; off <<= 1) {
        pl += __shfl_xor(pl, off, 64);
        pr += __shfl_xor(pr, off, 64);
      }
      if (l15 == 0 && mvalid) {
        el[m * HEADS + w] = pl;
        er[m * HEADS + w] = pr;
      }
    }
  }
}

// One wave per dst node. Phase 1 (softmax): lane = h*16 + j over the 16 edges.
// Phase 2 (gather): one dwordx4 covers 16B of a 512B fs row; 32 lanes = 1 row,
// so each load instruction fetches TWO rows (wave half = lane>>5 takes edges
// 2p+half). Pinned at the random-gather L2-miss ceiling (~443 MB fetch);
// structure-insensitive (two variants measured identical at 142 us).
__global__ __launch_bounds__(256, 4) void k_aggregate(
    const int* __restrict__ row_ptr, const int* __restrict__ col_ind,
    const float* __restrict__ el, const float* __restrict__ er,
    const unsigned short* __restrict__ fs_bf, float* __restrict__ out,
    int n_nodes) {
  const int gid = blockIdx.x * blockDim.x + threadIdx.x;
  const int node = gid >> 6;
  const int lane = threadIdx.x & 63;
  if (node >= n_nodes) return;

  const int h = lane >> 4;
  const int j = lane & 15;
  const int rs = row_ptr[node];
  const int deg = row_ptr[node + 1] - rs;  // == 16 by construction

  const bool valid = (j < deg);
  const int src = valid ? col_ind[rs + j] : 0;

  float e = valid ? (er[src * HEADS + h] + el[node * HEADS + h]) : -INFINITY;
  e = (e > 0.f) ? e : NEG_SLOPE * e;  // LeakyReLU

  float mx = e;
#pragma unroll
  for (int off = 1; off < 16; off <<= 1) mx = fmaxf(mx, __shfl_xor(mx, off, 64));
  float ex = valid ? __expf(e - mx) : 0.f;
  float s = ex;
#pragma unroll
  for (int off = 1; off < 16; off <<= 1) s += __shfl_xor(s, off, 64);
  const float a = ex / s;  // a == 0 for invalid edges (ex == 0)

  // ---- phase 2: hoisted two-row-per-load gather
  const int half = lane >> 5;   // 0: even edges, 1: odd edges
  const int li = lane & 31;     // 16B chunk index within the 512B row
  const int hd = li >> 3;       // head owning cols [li*8, li*8+8)

  int sj[8];
#pragma unroll
  for (int p = 0; p < 8; ++p) sj[p] = __shfl(src, 2 * p + half, 64);

  uint4 u[8];
#pragma unroll
  for (int p = 0; p < 8; ++p)
    u[p] = ((const uint4*)(fs_bf + (size_t)sj[p] * NOUT))[li];

  float wgt[8];
#pragma unroll
  for (int p = 0; p < 8; ++p)
    wgt[p] = __shfl(a, hd * 16 + 2 * p + half, 64);

  float acc[8];
#pragma unroll
  for (int k = 0; k < 8; ++k) acc[k] = 0.f;
#pragma unroll
  for (int p = 0; p < 8; ++p) {
    const uint4 v = u[p];
    const float w0 = wgt[p];
    acc[0] = fmaf(w0, __uint_as_float(v.x << 16), acc[0]);
    acc[1] = fmaf(w0, __uint_as_float(v.x & 0xFFFF0000u), acc[1]);
    acc[2] = fmaf(w0, __uint_as_float(v.y << 16), acc[2]);
    acc[3] = fmaf(w0, __uint_as_float(v.y & 0xFFFF0000u), acc[3]);
    acc[4] = fmaf(w0, __uint_as_float(v.z << 16), acc[4]);
    acc[5] = fmaf(w0, __uint_as_float(v.z & 0xFFFF0000u), acc[5]);
    acc[6] = fmaf(w0, __uint_as_float(v.w << 16), acc[6]);
    acc[7] = fmaf(w0, __uint_as_float(v.w & 0xFFFF0000u), acc[7]);
  }

  // combine the two edge-halves: lanes l and l^32 own the same col chunk
#pragma unroll
  for (int k = 0; k < 8; ++k) acc[k] += __shfl_xor(acc[k], 32, 64);

  // lane half 0 stores floats [li*8, li*8+4), half 1 stores [li*8+4, li*8+8)
  float4 o;
  o.x = half ? acc[4] : acc[0];
  o.y = half ? acc[5] : acc[1];
  o.z = half ? acc[6] : acc[2];
  o.w = half ? acc[7] : acc[3];
  *(float4*)(out + (size_t)node * NOUT + li * 8 + half * 4) = o;
}

extern "C" void kernel_launch(void* const* d_in, const int* in_sizes, int n_in,
                              void* d_out, int out_size, void* d_ws, size_t ws_size,
                              hipStream_t stream) {
  const int* row_ptr = (const int*)d_in[0];
  const int* col_ind = (const int*)d_in[1];
  const float* feat = (const float*)d_in[2];
  const float* W = (const float*)d_in[3];
  const float* attn_l = (const float*)d_in[4];
  const float* attn_r = (const float*)d_in[5];
  float* out = (float*)d_out;
  const int n_nodes = in_sizes[0] - 1;

  // Workspace: Wbf (128 KB) | feat_src bf16 (51.2 MB) | el, er (1.6 MB each)
  char* ws = (char*)d_ws;
  unsigned short* Wbf = (unsigned short*)ws;
  unsigned short* fs_bf = (unsigned short*)(ws + 128 * 1024);
  size_t fs_bytes = (size_t)n_nodes * NOUT * sizeof(unsigned short);
  float* el = (float*)(ws + 128 * 1024 + fs_bytes);
  float* er = el + (size_t)n_nodes * HEADS;

  // feat_bf scratch lives in d_out (51.2 MB <= 102.4 MB); dead once
  // k_aggregate starts overwriting out (kernels are stream-serialized).
  unsigned short* feat_bf = (unsigned short*)d_out;

  k_cast<<<2048, 256, 0, stream>>>(feat, W, feat_bf, Wbf, n_nodes * (KIN / 4));
  k_gemm_mfma<<<(n_nodes + 63) / 64, 256, 0, stream>>>(
      feat_bf, Wbf, attn_l, attn_r, fs_bf, el, er, n_nodes);
  k_aggregate<<<(n_nodes + 3) / 4, 256, 0, stream>>>(
      row_ptr, col_ind, el, er, fs_bf, out, n_nodes);
}

// Round 3
// 348.992 us; speedup vs baseline: 1.0552x; 1.0552x over previous
//
#include <hip/hip_runtime.h>
#include <math.h>

// GATConv forward:
//   k_cast_w    : Wbf[n][k] = bf16(W[n][k])  (W is [HD=256][IN=256]; this IS
//                 B^T layout for feat @ W.T, so no transpose needed)
//   k_gemm_mfma : feat_src(bf16) = feat @ W.T via mfma_f32_16x16x32_bf16.
//                 fp32 A is loaded per-block (each block only reads its own 64
//                 rows), converted bf16 in-register (RNE), and written into an
//                 XOR-swizzled LDS tile (write-side j^(r&7), read-side same
//                 formula -- both-sides rule). BK=64, double-buffered, ONE
//                 barrier per chunk, next-chunk global loads issued before the
//                 barrier (T14 split). B fragments straight from L2-hot Wbf.
//                 Fused el/er epilogue. No separate feat cast pass.
//   k_aggregate : per-dst edge softmax (deg==16) + weighted bf16 gather-sum.
//                 Pinned at the random-gather L2/L3 ceiling (~443 MB fetch,
//                 142 us) -- proven occupancy- and structure-insensitive
//                 across three measured variants. Unchanged.
//
// N=100000, IN=256, H=4, D=64, E=N*16; degree uniformly 16 (row_ptr=arange*16).

#define HEADS 4
#define KIN 256
#define NOUT 256   // H*D
#define NEG_SLOPE 0.2f

typedef __attribute__((ext_vector_type(4))) short short4v;
typedef __attribute__((ext_vector_type(8))) short short8v;
typedef __attribute__((ext_vector_type(4))) float floatx4;

static __device__ __forceinline__ unsigned short f2bf(float x) {
  // round-to-nearest-even fp32 -> bf16 (inputs are normal; no NaN handling)
  unsigned u = __float_as_uint(x);
  u += 0x7FFFu + ((u >> 16) & 1u);
  return (unsigned short)(u >> 16);
}
static __device__ __forceinline__ float bf2f(unsigned short b) {
  return __uint_as_float(((unsigned)b) << 16);
}

__global__ __launch_bounds__(256) void k_cast_w(const float* __restrict__ W,
                                                unsigned short* __restrict__ Wbf) {
  const int i = blockIdx.x * 256 + threadIdx.x;  // float4 index, 16384 total
  float4 f = ((const float4*)W)[i];
  ushort4 o;
  o.x = f2bf(f.x); o.y = f2bf(f.y); o.z = f2bf(f.z); o.w = f2bf(f.w);
  ((ushort4*)Wbf)[i] = o;
}

// Block = 256 threads = 4 waves. Block tile: M=64 rows, N=256 (full width).
// Wave w owns cols [64w, 64w+64) == head w. Per wave: 4x4 grid of 16x16 MFMA
// tiles, K in 4 chunks of 64 (2 MFMA k-steps each).
//
// A LDS: bf16 [64 rows][64 k] per buffer (8 KB), 16B granule j of row r stored
// at granule j ^ (r&7)  -> the stride-128B fragment read (16 lanes, same k-
// granule, consecutive rows) spreads across all banks (2-way alias only).
__global__ __launch_bounds__(256, 2) void k_gemm_mfma(
    const float* __restrict__ feat, const unsigned short* __restrict__ Wbf,
    const float* __restrict__ attn_l, const float* __restrict__ attn_r,
    unsigned short* __restrict__ fs_bf, float* __restrict__ el,
    float* __restrict__ er, int n_nodes) {
  __shared__ unsigned short Alds[2][64 * 64];  // 2 x 8 KB bf16

  const int tid = threadIdx.x;
  const int lane = tid & 63;
  const int w = tid >> 6;      // wave = head = col-group
  const int m0 = blockIdx.x * 64;
  const int q = lane >> 4;     // quad 0..3
  const int l15 = lane & 15;

  floatx4 acc[4][4];
#pragma unroll
  for (int mt = 0; mt < 4; ++mt)
#pragma unroll
    for (int nt = 0; nt < 4; ++nt)
#pragma unroll
      for (int r = 0; r < 4; ++r) acc[mt][nt][r] = 0.0f;

  // ---- A staging map: thread t -> row ar = t>>2, float window (t&3)*16..+16
  // (4 coalesced float4 loads per chunk); owns bf16 granules 2(t&3), 2(t&3)+1.
  const int ar = tid >> 2;
  const int aj = tid & 3;
  const int r7 = ar & 7;
  int agr = m0 + ar;
  if (agr >= n_nodes) agr = n_nodes - 1;  // clamp tail (rows unused below)
  const float* __restrict__ abase = feat + (size_t)agr * KIN + aj * 16;
  unsigned short* const aw0 = &Alds[0][ar * 64 + ((2 * aj + 0) ^ r7) * 8];
  unsigned short* const aw1 = &Alds[0][ar * 64 + ((2 * aj + 1) ^ r7) * 8];
  const int bufoff = 64 * 64;  // elems between buffer 0 and 1

  float4 rg[2][4];  // two reg-staging buffers (indices fold: loop is unrolled)

#pragma unroll
  for (int i = 0; i < 4; ++i) rg[0][i] = *(const float4*)(abase + i * 4);

#pragma unroll
  for (int kc = 0; kc < 4; ++kc) {
    const int b = kc & 1;
    // ---- convert + swizzled LDS write of chunk kc from regs
    {
      const float4* R = rg[b];
      short8v g0, g1;
      g0[0] = (short)f2bf(R[0].x); g0[1] = (short)f2bf(R[0].y);
      g0[2] = (short)f2bf(R[0].z); g0[3] = (short)f2bf(R[0].w);
      g0[4] = (short)f2bf(R[1].x); g0[5] = (short)f2bf(R[1].y);
      g0[6] = (short)f2bf(R[1].z); g0[7] = (short)f2bf(R[1].w);
      g1[0] = (short)f2bf(R[2].x); g1[1] = (short)f2bf(R[2].y);
      g1[2] = (short)f2bf(R[2].z); g1[3] = (short)f2bf(R[2].w);
      g1[4] = (short)f2bf(R[3].x); g1[5] = (short)f2bf(R[3].y);
      g1[6] = (short)f2bf(R[3].z); g1[7] = (short)f2bf(R[3].w);
      *(short8v*)(aw0 + b * bufoff) = g0;
      *(short8v*)(aw1 + b * bufoff) = g1;
    }
    // ---- issue next chunk's global loads (latency hides under barrier+MFMA)
    if (kc < 3) {
      const float* p = abase + (kc + 1) * 64;
#pragma unroll
      for (int i = 0; i < 4; ++i) rg[(kc + 1) & 1][i] = *(const float4*)(p + i * 4);
    }
    __syncthreads();  // chunk kc visible to all; prev buffer free for reuse

    // ---- B fragments straight from L2-hot Wbf:
    // lane(q,l15) needs B[n = 64w+16nt+l15][k = 64kc+32ks+8q .. +8]
    short8v bfr[2][4];
#pragma unroll
    for (int ks = 0; ks < 2; ++ks)
#pragma unroll
      for (int nt = 0; nt < 4; ++nt)
        bfr[ks][nt] = *(const short8v*)(Wbf + (size_t)(w * 64 + nt * 16 + l15) * KIN +
                                        kc * 64 + ks * 32 + q * 8);

#pragma unroll
    for (int ks = 0; ks < 2; ++ks) {
      short8v af[4];
#pragma unroll
      for (int mt = 0; mt < 4; ++mt) {
        const int slot = (ks * 4 + q) ^ (l15 & 7);  // un-swizzle on read
        af[mt] = *(const short8v*)(&Alds[b][(mt * 16 + l15) * 64 + slot * 8]);
      }
#pragma unroll
      for (int mt = 0; mt < 4; ++mt)
#pragma unroll
        for (int nt = 0; nt < 4; ++nt)
          acc[mt][nt] = __builtin_amdgcn_mfma_f32_16x16x32_bf16(
              af[mt], bfr[ks][nt], acc[mt][nt], 0, 0, 0);
    }
  }

  // ---- epilogue: C/D layout col = l15, row = q*4 + r (per 16x16 tile).
  // Store feat_src (bf16) + el/er from fp32 accumulators.
  float alv[4], arv[4];
#pragma unroll
  for (int nt = 0; nt < 4; ++nt) {
    alv[nt] = attn_l[w * 64 + nt * 16 + l15];
    arv[nt] = attn_r[w * 64 + nt * 16 + l15];
  }
#pragma unroll
  for (int mt = 0; mt < 4; ++mt) {
#pragma unroll
    for (int r = 0; r < 4; ++r) {
      const int m = m0 + mt * 16 + q * 4 + r;
      const bool mvalid = (m < n_nodes);
      float pl = 0.f, pr = 0.f;
#pragma unroll
      for (int nt = 0; nt < 4; ++nt) {
        const float v = acc[mt][nt][r];
        pl = fmaf(v, alv[nt], pl);
        pr = fmaf(v, arv[nt], pr);
        if (mvalid)
          fs_bf[(size_t)m * NOUT + w * 64 + nt * 16 + l15] = f2bf(v);
      }
      // reduce over the 16 lanes of this quad (same row m)
#pragma unroll
      for (int off = 1; off < 16; off <<= 1) {
        pl += __shfl_xor(pl, off, 64);
        pr += __shfl_xor(pr, off, 64);
      }
      if (l15 == 0 && mvalid) {
        el[m * HEADS + w] = pl;
        er[m * HEADS + w] = pr;
      }
    }
  }
}

// One wave per dst node. Phase 1 (softmax): lane = h*16 + j over the 16 edges.
// Phase 2 (gather): one dwordx4 covers 16B of a 512B fs row; 32 lanes = 1 row,
// so each load instruction fetches TWO rows (wave half = lane>>5 takes edges
// 2p+half). Pinned at the random-gather L2/L3 ceiling (~443 MB fetch, 142 us);
// occupancy- and structure-insensitive (3 variants measured identical).
__global__ __launch_bounds__(256, 4) void k_aggregate(
    const int* __restrict__ row_ptr, const int* __restrict__ col_ind,
    const float* __restrict__ el, const float* __restrict__ er,
    const unsigned short* __restrict__ fs_bf, float* __restrict__ out,
    int n_nodes) {
  const int gid = blockIdx.x * blockDim.x + threadIdx.x;
  const int node = gid >> 6;
  const int lane = threadIdx.x & 63;
  if (node >= n_nodes) return;

  const int h = lane >> 4;
  const int j = lane & 15;
  const int rs = row_ptr[node];
  const int deg = row_ptr[node + 1] - rs;  // == 16 by construction

  const bool valid = (j < deg);
  const int src = valid ? col_ind[rs + j] : 0;

  float e = valid ? (er[src * HEADS + h] + el[node * HEADS + h]) : -INFINITY;
  e = (e > 0.f) ? e : NEG_SLOPE * e;  // LeakyReLU

  float mx = e;
#pragma unroll
  for (int off = 1; off < 16; off <<= 1) mx = fmaxf(mx, __shfl_xor(mx, off, 64));
  float ex = valid ? __expf(e - mx) : 0.f;
  float s = ex;
#pragma unroll
  for (int off = 1; off < 16; off <<= 1) s += __shfl_xor(s, off, 64);
  const float a = ex / s;  // a == 0 for invalid edges (ex == 0)

  // ---- phase 2: hoisted two-row-per-load gather
  const int half = lane >> 5;   // 0: even edges, 1: odd edges
  const int li = lane & 31;     // 16B chunk index within the 512B row
  const int hd = li >> 3;       // head owning cols [li*8, li*8+8)

  int sj[8];
#pragma unroll
  for (int p = 0; p < 8; ++p) sj[p] = __shfl(src, 2 * p + half, 64);

  uint4 u[8];
#pragma unroll
  for (int p = 0; p < 8; ++p)
    u[p] = ((const uint4*)(fs_bf + (size_t)sj[p] * NOUT))[li];

  float wgt[8];
#pragma unroll
  for (int p = 0; p < 8; ++p)
    wgt[p] = __shfl(a, hd * 16 + 2 * p + half, 64);

  float acc[8];
#pragma unroll
  for (int k = 0; k < 8; ++k) acc[k] = 0.f;
#pragma unroll
  for (int p = 0; p < 8; ++p) {
    const uint4 v = u[p];
    const float w0 = wgt[p];
    acc[0] = fmaf(w0, __uint_as_float(v.x << 16), acc[0]);
    acc[1] = fmaf(w0, __uint_as_float(v.x & 0xFFFF0000u), acc[1]);
    acc[2] = fmaf(w0, __uint_as_float(v.y << 16), acc[2]);
    acc[3] = fmaf(w0, __uint_as_float(v.y & 0xFFFF0000u), acc[3]);
    acc[4] = fmaf(w0, __uint_as_float(v.z << 16), acc[4]);
    acc[5] = fmaf(w0, __uint_as_float(v.z & 0xFFFF0000u), acc[5]);
    acc[6] = fmaf(w0, __uint_as_float(v.w << 16), acc[6]);
    acc[7] = fmaf(w0, __uint_as_float(v.w & 0xFFFF0000u), acc[7]);
  }

  // combine the two edge-halves: lanes l and l^32 own the same col chunk
#pragma unroll
  for (int k = 0; k < 8; ++k) acc[k] += __shfl_xor(acc[k], 32, 64);

  // lane half 0 stores floats [li*8, li*8+4), half 1 stores [li*8+4, li*8+8)
  // (static indexing only -- runtime-indexed acc would spill to scratch)
  float4 o;
  o.x = half ? acc[4] : acc[0];
  o.y = half ? acc[5] : acc[1];
  o.z = half ? acc[6] : acc[2];
  o.w = half ? acc[7] : acc[3];
  *(float4*)(out + (size_t)node * NOUT + li * 8 + half * 4) = o;
}

extern "C" void kernel_launch(void* const* d_in, const int* in_sizes, int n_in,
                              void* d_out, int out_size, void* d_ws, size_t ws_size,
                              hipStream_t stream) {
  const int* row_ptr = (const int*)d_in[0];
  const int* col_ind = (const int*)d_in[1];
  const float* feat = (const float*)d_in[2];
  const float* W = (const float*)d_in[3];
  const float* attn_l = (const float*)d_in[4];
  const float* attn_r = (const float*)d_in[5];
  float* out = (float*)d_out;
  const int n_nodes = in_sizes[0] - 1;

  // Workspace: Wbf (128 KB) | feat_src bf16 (51.2 MB) | el, er (1.6 MB each)
  char* ws = (char*)d_ws;
  unsigned short* Wbf = (unsigned short*)ws;
  unsigned short* fs_bf = (unsigned short*)(ws + 128 * 1024);
  size_t fs_bytes = (size_t)n_nodes * NOUT * sizeof(unsigned short);
  float* el = (float*)(ws + 128 * 1024 + fs_bytes);
  float* er = el + (size_t)n_nodes * HEADS;

  k_cast_w<<<64, 256, 0, stream>>>(W, Wbf);
  k_gemm_mfma<<<(n_nodes + 63) / 64, 256, 0, stream>>>(
      feat, Wbf, attn_l, attn_r, fs_bf, el, er, n_nodes);
  k_aggregate<<<(n_nodes + 3) / 4, 256, 0, stream>>>(
      row_ptr, col_ind, el, er, fs_bf, out, n_nodes);
}